// Round 8
// baseline (7221.096 us; speedup 1.0000x reference)
//
#include <hip/hip_runtime.h>
#include <stdint.h>

// Problem dims (fixed by setup_inputs)
#define BB 8
#define SS 2048
#define DD 1024
#define HH 4096
#define MM 256

typedef short bf16x8 __attribute__((ext_vector_type(8)));   // 8 bf16 in 4 VGPRs
typedef float f32x4 __attribute__((ext_vector_type(4)));

__device__ inline unsigned short f2bf(float f){
  unsigned u = __builtin_bit_cast(unsigned, f);
  return (unsigned short)((u + 0x7FFFu + ((u >> 16) & 1u)) >> 16);  // RNE
}

// ---------------- pack f32 -> bf16 (4 elems/thread) ----------------
__global__ void ssma_pack_bf16(const float* __restrict__ src,
                               unsigned short* __restrict__ dst, int n4){
  int i = blockIdx.x * blockDim.x + threadIdx.x;
  if (i < n4){
    float4 v = ((const float4*)src)[i];
    ushort4 o;
    o.x = f2bf(v.x); o.y = f2bf(v.y); o.z = f2bf(v.z); o.w = f2bf(v.w);
    ((ushort4*)dst)[i] = o;
  }
}

// ---------------- bf16 MFMA GEMM, C = A * B^T (+epilogue) ----------------
template<int EPI>
__global__ __launch_bounds__(256) void ssma_gemm_bt(
    const unsigned short* __restrict__ A, const unsigned short* __restrict__ Bw,
    int K, int N, const float* __restrict__ bias,
    const float* __restrict__ resid, void* __restrict__ Cout)
{
  __shared__ uint4 As4[512];   // 128x32 bf16 = 8KB
  __shared__ uint4 Bs4[512];
  unsigned short* As = (unsigned short*)As4;
  unsigned short* Bs = (unsigned short*)Bs4;

  const int tid  = threadIdx.x;
  const int lane = tid & 63;
  const int wv   = tid >> 6;
  const int wm   = wv >> 1, wn = wv & 1;      // 2x2 wave grid, 64x64 per wave
  const int m0   = blockIdx.y * 128;
  const int n0   = blockIdx.x * 128;
  const int kq   = lane >> 4;
  const int rl   = lane & 15;

  f32x4 acc[4][4];
#pragma unroll
  for (int a = 0; a < 4; ++a)
#pragma unroll
    for (int b = 0; b < 4; ++b) acc[a][b] = (f32x4){0.f, 0.f, 0.f, 0.f};

  for (int k0 = 0; k0 < K; k0 += 32){
    __syncthreads();
#pragma unroll
    for (int i = 0; i < 2; ++i){
      int c  = tid + 256 * i;
      int r  = c >> 2;
      int c8 = (c & 3) * 8;
      As4[c] = *(const uint4*)(A  + (size_t)(m0 + r) * K + k0 + c8);
      Bs4[c] = *(const uint4*)(Bw + (size_t)(n0 + r) * K + k0 + c8);
    }
    __syncthreads();

    const bf16x8* Ap = (const bf16x8*)As;
    const bf16x8* Bp = (const bf16x8*)Bs;
    bf16x8 af[4], bfr[4];
#pragma unroll
    for (int mi = 0; mi < 4; ++mi) af[mi]  = Ap[(wm * 64 + mi * 16 + rl) * 4 + kq];
#pragma unroll
    for (int ni = 0; ni < 4; ++ni) bfr[ni] = Bp[(wn * 64 + ni * 16 + rl) * 4 + kq];
#pragma unroll
    for (int mi = 0; mi < 4; ++mi)
#pragma unroll
      for (int ni = 0; ni < 4; ++ni)
        acc[mi][ni] = __builtin_amdgcn_mfma_f32_16x16x32_bf16(af[mi], bfr[ni], acc[mi][ni], 0, 0, 0);
  }

#pragma unroll
  for (int mi = 0; mi < 4; ++mi){
#pragma unroll
    for (int ni = 0; ni < 4; ++ni){
      int col = n0 + wn * 64 + ni * 16 + rl;
      float bv = bias[col];
#pragma unroll
      for (int r = 0; r < 4; ++r){
        int row = m0 + wm * 64 + mi * 16 + kq * 4 + r;
        float v = acc[mi][ni][r] + bv;
        if (EPI == 0){
          v = fmaxf(v, 0.0f);
          ((unsigned short*)Cout)[(size_t)row * N + col] = f2bf(v);
        } else {
          v += resid[(size_t)row * N + col];
          ((float*)Cout)[(size_t)row * N + col] = v;
        }
      }
    }
  }
}

// ---------------- exact-f32 GEMM: xproj = x * win_w^T + win_b ----------------
__global__ __launch_bounds__(256) void ssma_gemm3_f32(
    const float* __restrict__ A, const float* __restrict__ Bw,
    const float* __restrict__ bias, float* __restrict__ C)
{
  __shared__ float As[64][17];
  __shared__ float Bs[64][17];
  const int tid = threadIdx.x;
  const int tx = tid & 15, ty = tid >> 4;
  const int m0 = blockIdx.y * 64, n0 = blockIdx.x * 64;
  float acc[4][4];
#pragma unroll
  for (int i = 0; i < 4; ++i)
#pragma unroll
    for (int j = 0; j < 4; ++j) acc[i][j] = 0.f;

  for (int k0 = 0; k0 < DD; k0 += 16){
    __syncthreads();
#pragma unroll
    for (int i = 0; i < 4; ++i){
      int e = tid + 256 * i;
      int r = e >> 4, c = e & 15;
      As[r][c] = A [(size_t)(m0 + r) * DD + k0 + c];
      Bs[r][c] = Bw[(size_t)(n0 + r) * DD + k0 + c];
    }
    __syncthreads();
#pragma unroll
    for (int kk = 0; kk < 16; ++kk){
      float a[4], b[4];
#pragma unroll
      for (int i = 0; i < 4; ++i) a[i] = As[ty * 4 + i][kk];
#pragma unroll
      for (int j = 0; j < 4; ++j) b[j] = Bs[tx * 4 + j][kk];
#pragma unroll
      for (int i = 0; i < 4; ++i)
#pragma unroll
        for (int j = 0; j < 4; ++j) acc[i][j] = fmaf(a[i], b[j], acc[i][j]);
    }
  }
#pragma unroll
  for (int i = 0; i < 4; ++i){
    int row = m0 + ty * 4 + i;
#pragma unroll
    for (int j = 0; j < 4; ++j){
      int col = n0 + tx * 4 + j;
      C[(size_t)row * MM + col] = acc[i][j] + bias[col];
    }
  }
}

// ---------------- 256x256 f32 transpose (wstate -> wT) ----------------
__global__ __launch_bounds__(256) void ssma_transpose(
    const float* __restrict__ A, float* __restrict__ At)
{
  __shared__ float t[32][33];
  const int tx = threadIdx.x & 31, ty = threadIdx.x >> 5;  // 32x8
  const int x0 = blockIdx.x * 32, y0 = blockIdx.y * 32;
#pragma unroll
  for (int r = 0; r < 32; r += 8)
    t[ty + r][tx] = A[(size_t)(y0 + ty + r) * MM + x0 + tx];
  __syncthreads();
#pragma unroll
  for (int r = 0; r < 32; r += 8)
    At[(size_t)(x0 + ty + r) * MM + y0 + tx] = t[tx][ty + r];
}

// ---------------- sequential top-k gated scan, v7: WAVE-SYNCHRONOUS ----------------
// 8 blocks x 64 threads: one wave per batch; rows m = 4*lane+i.
// NO multi-wave barriers; all cross-lane via ballot/shfl + same-wave LDS
// (DS pipe is in-order per wave; __syncthreads on a 1-wave block ~free).
// Per step: matvec (32 coalesced float4 gathers of wT kept rows) -> exponent
// hist (wave-private LDS atomics) -> shfl suffix-scan -> bin gate ->
// boundary refine (ballot-prefix cand list) -> EMA -> kept-list rebuild.
// Exact f32, exact strict-rank (== reference v>=thr tie rule), deterministic.
__global__ __launch_bounds__(64, 1) void ssma_scan7(
    const float* __restrict__ xproj, const float* __restrict__ state,
    const float* __restrict__ wT, const float* __restrict__ gamma_p,
    const int* __restrict__ topk_p, float* __restrict__ mem_out)
{
  __shared__ __align__(16) int   kidx[MM + 32];   // j<<8 (float offset of wT row)
  __shared__ __align__(16) float kval[MM + 32];
  __shared__ __align__(16) int   hist[256];
  __shared__ __align__(16) int   sufg[256];
  __shared__ __align__(16) float cand[256 + 16];

  const int lane = threadIdx.x;          // 0..63
  const int b    = blockIdx.x;
  const float gamma = *gamma_p;
  const float omg   = 1.0f - gamma;
  const int   K     = *topk_p;

  const float* xp  = xproj + (size_t)b * SS * MM;
  const float* wT4 = wT + 4 * lane;      // float4 gather base (rows 4l..4l+3)

  float4 mem = ((const float4*)(state + b * MM))[lane];
  ((int4*)hist)[lane] = (int4){0, 0, 0, 0};

  int nkp;
  // build kept list from values gv[0..3] with predicates pr[0..3]; (lane,i) order
#define BUILD_LIST(GV, PR)                                                  \
  { int cl = (PR[0]?1:0) + (PR[1]?1:0) + (PR[2]?1:0) + (PR[3]?1:0);         \
    int inc = cl;                                                           \
    _Pragma("unroll")                                                       \
    for (int off = 1; off < 64; off <<= 1){                                 \
      int xv = __shfl_up(inc, off);                                        \
      if (lane >= off) inc += xv;                                           \
    }                                                                       \
    int nk = __shfl(inc, 63);                                               \
    int pp = inc - cl;                                                      \
    if (PR[0]){ kidx[pp] = (4*lane+0) << 8; kval[pp] = GV[0]; ++pp; }       \
    if (PR[1]){ kidx[pp] = (4*lane+1) << 8; kval[pp] = GV[1]; ++pp; }       \
    if (PR[2]){ kidx[pp] = (4*lane+2) << 8; kval[pp] = GV[2]; ++pp; }       \
    if (PR[3]){ kidx[pp] = (4*lane+3) << 8; kval[pp] = GV[3]; ++pp; }       \
    nkp = (nk + 3) & ~3; if (nkp < 32) nkp = 32;                            \
    if (lane < nkp - nk){ kidx[nk + lane] = 0; kval[nk + lane] = 0.0f; }    \
  }

  {
    float gv0[4] = {mem.x, mem.y, mem.z, mem.w};
    bool  pr0[4] = {mem.x != 0.f, mem.y != 0.f, mem.z != 0.f, mem.w != 0.f};
    BUILD_LIST(gv0, pr0)
  }
  float4 xpc = ((const float4*)xp)[lane];
  __syncthreads();

  // one gather slot: 4 kept rows -> 4 float4 weight loads + 16 FMA
#define SLOT(ACC, II, VV) {                                                 \
    const float4 w0s = *(const float4*)(wT4 + (II).x);                      \
    const float4 w1s = *(const float4*)(wT4 + (II).y);                      \
    const float4 w2s = *(const float4*)(wT4 + (II).z);                      \
    const float4 w3s = *(const float4*)(wT4 + (II).w);                      \
    ACC.x = fmaf(w3s.x,(VV).w, fmaf(w2s.x,(VV).z, fmaf(w1s.x,(VV).y, fmaf(w0s.x,(VV).x, ACC.x)))); \
    ACC.y = fmaf(w3s.y,(VV).w, fmaf(w2s.y,(VV).z, fmaf(w1s.y,(VV).y, fmaf(w0s.y,(VV).x, ACC.y)))); \
    ACC.z = fmaf(w3s.z,(VV).w, fmaf(w2s.z,(VV).z, fmaf(w1s.z,(VV).y, fmaf(w0s.z,(VV).x, ACC.z)))); \
    ACC.w = fmaf(w3s.w,(VV).w, fmaf(w2s.w,(VV).z, fmaf(w1s.w,(VV).y, fmaf(w0s.w,(VV).x, ACC.w)))); }

  for (int t = 0; t < SS; ++t){
    // ---------- phase A: sparse matvec ----------
    const int4*   ip = (const int4*)kidx;
    const float4* vp = (const float4*)kval;
    int4   I0 = ip[0], I1 = ip[1], I2 = ip[2], I3 = ip[3];
    int4   I4 = ip[4], I5 = ip[5], I6 = ip[6], I7 = ip[7];
    float4 V0 = vp[0], V1 = vp[1], V2 = vp[2], V3 = vp[3];
    float4 V4 = vp[4], V5 = vp[5], V6 = vp[6], V7 = vp[7];
    float4 accA = {0.f,0.f,0.f,0.f}, accB = {0.f,0.f,0.f,0.f};
    SLOT(accA, I0, V0) SLOT(accB, I1, V1) SLOT(accA, I2, V2) SLOT(accB, I3, V3)
    SLOT(accA, I4, V4) SLOT(accB, I5, V5) SLOT(accA, I6, V6) SLOT(accB, I7, V7)
    if (nkp > 32){                       // rare tie-overflow
      for (int s = 8; s < (nkp >> 2); ++s){
        int4 Ix = ip[s]; float4 Vx = vp[s];
        SLOT(accA, Ix, Vx)
      }
    }
    float4 su;
    su.x = fmaxf(accA.x + accB.x + xpc.x, 0.f);
    su.y = fmaxf(accA.y + accB.y + xpc.y, 0.f);
    su.z = fmaxf(accA.z + accB.z + xpc.z, 0.f);
    su.w = fmaxf(accA.w + accB.w + xpc.w, 0.f);

    int tn = (t + 1 < SS) ? t + 1 : SS - 1;
    float4 xpn = ((const float4*)(xp + (size_t)tn * MM))[lane];

    // ---------- hist build ----------
    float sv[4] = {su.x, su.y, su.z, su.w};
    int   bn[4];
#pragma unroll
    for (int i = 0; i < 4; ++i){
      bn[i] = (int)(__float_as_uint(sv[i]) >> 23);
      if (sv[i] > 0.f) atomicAdd(&hist[bn[i]], 1);
    }
    __syncthreads();

    // ---------- suffix scan (count in strictly-higher bins) ----------
    int4 h4 = ((const int4*)hist)[lane];
    int tot = h4.x + h4.y + h4.z + h4.w;
    int inc2 = tot;
#pragma unroll
    for (int off = 1; off < 64; off <<= 1){
      int xv = __shfl_down(inc2, off);
      inc2 += (lane + off < 64) ? xv : 0;
    }
    int E = inc2 - tot;                  // sum over lanes > l
    int4 s4;
    s4.w = E;
    s4.z = E + h4.w;
    s4.y = s4.z + h4.z;
    s4.x = s4.y + h4.y;
    ((int4*)sufg)[lane] = s4;
    __syncthreads();

    // ---------- bin-level gate ----------
    float g[4] = {0.f, 0.f, 0.f, 0.f};
    int   av[4];
    bool  bd[4] = {false, false, false, false};
#pragma unroll
    for (int i = 0; i < 4; ++i){
      av[i] = 0;
      if (sv[i] > 0.f){
        int a  = sufg[bn[i]];
        int hb = hist[bn[i]];
        av[i] = a;
        if (a >= K)           g[i] = 0.f;
        else if (a + hb <= K) g[i] = sv[i];
        else                  bd[i] = true;
      }
    }

    // ---------- boundary refine (single straddling bin) ----------
    {
      int cb = (bd[0]?1:0) + (bd[1]?1:0) + (bd[2]?1:0) + (bd[3]?1:0);
      int incb = cb;
#pragma unroll
      for (int off = 1; off < 64; off <<= 1){
        int xv = __shfl_up(incb, off);
        if (lane >= off) incb += xv;
      }
      int Btot = __shfl(incb, 63);
      if (Btot > 0){
        int pb = incb - cb;
#pragma unroll
        for (int i = 0; i < 4; ++i)
          if (bd[i]) cand[pb++] = sv[i];
        int Bpad = (Btot + 3) & ~3;
        if (lane < Bpad - Btot) cand[Btot + lane] = 0.0f;
        __syncthreads();
        int nch = Bpad >> 2;
        int w[4] = {0, 0, 0, 0};
        const float4* cp = (const float4*)cand;
        for (int c2 = 0; c2 < nch; ++c2){
          float4 v = cp[c2];
#pragma unroll
          for (int i = 0; i < 4; ++i)
            w[i] += (v.x > sv[i]) + (v.y > sv[i]) + (v.z > sv[i]) + (v.w > sv[i]);
        }
#pragma unroll
        for (int i = 0; i < 4; ++i)
          if (bd[i]) g[i] = (av[i] + w[i] <= K - 1) ? sv[i] : 0.f;
      }
    }

    // ---------- EMA ----------
    mem.x = fmaf(gamma, mem.x, omg * g[0]);
    mem.y = fmaf(gamma, mem.y, omg * g[1]);
    mem.z = fmaf(gamma, mem.z, omg * g[2]);
    mem.w = fmaf(gamma, mem.w, omg * g[3]);

    // ---------- zero hist for next step (DS pipe in-order per wave) ----------
    ((int4*)hist)[lane] = (int4){0, 0, 0, 0};

    // ---------- rebuild kept list ----------
    {
      bool pr[4] = {g[0] > 0.f, g[1] > 0.f, g[2] > 0.f, g[3] > 0.f};
      BUILD_LIST(g, pr)
    }
    xpc = xpn;
    __syncthreads();
  }
  ((float4*)(mem_out + b * MM))[lane] = mem;
#undef SLOT
#undef BUILD_LIST
}

extern "C" void kernel_launch(void* const* d_in, const int* in_sizes, int n_in,
                              void* d_out, int out_size, void* d_ws, size_t ws_size,
                              hipStream_t stream)
{
  const float* x      = (const float*)d_in[0];
  const float* state  = (const float*)d_in[1];
  // d_in[2]=U_w, d_in[3]=V_w unused by the reference
  const float* w1     = (const float*)d_in[4];
  const float* b1     = (const float*)d_in[5];
  const float* w2     = (const float*)d_in[6];
  const float* b2     = (const float*)d_in[7];
  const float* win_w  = (const float*)d_in[8];
  const float* win_b  = (const float*)d_in[9];
  const float* wstate = (const float*)d_in[10];
  const float* gammap = (const float*)d_in[11];
  const int*   topkp  = (const int*)d_in[12];

  float* out  = (float*)d_out;                       // (8,2048,1024)
  float* memo = out + (size_t)BB * SS * DD;          // (8,256)

  char* ws = (char*)d_ws;
  unsigned short* xb   = (unsigned short*)(ws);                   // 32 MB
  unsigned short* w1b  = (unsigned short*)(ws + 33554432);        // 8 MB (reused for wT after gemm1)
  unsigned short* w2b  = (unsigned short*)(ws + 41943040);        // 8 MB
  unsigned short* hbuf = (unsigned short*)(ws + 50331648);        // 128 MB
  float*          xprj = (float*)(ws + 184549376);                // 16 MB
  float*          wT   = (float*)(ws + 33554432);                 // 256 KB, after gemm1

  ssma_pack_bf16<<<16384, 256, 0, stream>>>(x,  xb,  4194304);
  ssma_pack_bf16<<<4096,  256, 0, stream>>>(w1, w1b, 1048576);
  ssma_pack_bf16<<<4096,  256, 0, stream>>>(w2, w2b, 1048576);

  ssma_gemm3_f32<<<dim3(4, 256), 256, 0, stream>>>(x, win_w, win_b, xprj);

  // h = relu(x*w1^T + b1): M=16384, N=4096, K=1024
  ssma_gemm_bt<0><<<dim3(32, 128), 256, 0, stream>>>(xb, w1b, 1024, 4096, b1, nullptr, (void*)hbuf);

  // wT = wstate^T (w1b region is dead after gemm1)
  ssma_transpose<<<dim3(8, 8), 256, 0, stream>>>(wstate, wT);

  // out = x + h*w2^T + b2: M=16384, N=1024, K=4096
  ssma_gemm_bt<1><<<dim3(8, 128), 256, 0, stream>>>(hbuf, w2b, 4096, 1024, b2, x, (void*)out);

  ssma_scan7<<<BB, 64, 0, stream>>>(xprj, state, wT, gammap, topkp, memo);
}